// Round 3
// baseline (770.862 us; speedup 1.0000x reference)
//
#include <hip/hip_runtime.h>
#include <math.h>

#define D_MODEL 256
#define NHEAD 8
#define HDIM 32
#define NLVL 4
#define NPTS 4
#define DFF 1024
#define NLAYERS 6
#define LEN 3060
#define BS 2
#define MROWS (BS * LEN)   // 6120
#define MPAD 6144          // padded rows for GEMM A operands

typedef __attribute__((ext_vector_type(8))) short bf16x8;
typedef __attribute__((ext_vector_type(4))) float f32x4;

__device__ __forceinline__ unsigned short f2bf(float f) {
    union { float f; unsigned u; } v; v.f = f;
    unsigned r = v.u + 0x7FFF + ((v.u >> 16) & 1);
    return (unsigned short)(r >> 16);
}
__device__ __forceinline__ float bf2f(unsigned short s) {
    union { unsigned u; float f; } v; v.u = ((unsigned)s) << 16;
    return v.f;
}

#define GLDS(gp, lp) __builtin_amdgcn_global_load_lds(                        \
    (const __attribute__((address_space(1))) void*)(gp),                      \
    (__attribute__((address_space(3))) void*)(lp), 16, 0, 0)

// ---------------------------------------------------------------------------
// Flatten: src levels -> out fp32 + outbf + qbf(out+pos) + pos fp32
// ---------------------------------------------------------------------------
__global__ __launch_bounds__(256) void flatten_kernel(
    const float* __restrict__ s0, const float* __restrict__ s1,
    const float* __restrict__ s2, const float* __restrict__ s3,
    const float* __restrict__ p0, const float* __restrict__ p1,
    const float* __restrict__ p2, const float* __restrict__ p3,
    const float* __restrict__ lemb,
    float* __restrict__ out, unsigned short* __restrict__ outbf,
    unsigned short* __restrict__ qbf, float* __restrict__ pos)
{
    int gid = blockIdx.x * 256 + threadIdx.x;
    if (gid >= MROWS * D_MODEL) return;
    int d  = gid & (D_MODEL - 1);
    int bt = gid >> 8;
    int b  = (bt >= LEN) ? 1 : 0;
    int t  = bt - b * LEN;

    int lv, li, hw;
    const float* sp; const float* pp;
    if (t < 2304)      { lv = 0; li = t;        hw = 2304; sp = s0; pp = p0; }
    else if (t < 2880) { lv = 1; li = t - 2304; hw = 576;  sp = s1; pp = p1; }
    else if (t < 3024) { lv = 2; li = t - 2880; hw = 144;  sp = s2; pp = p2; }
    else               { lv = 3; li = t - 3024; hw = 36;   sp = s3; pp = p3; }

    size_t si = (size_t)(b * D_MODEL + d) * hw + li;
    float v = sp[si];
    float pv = pp[si] + lemb[lv * D_MODEL + d];
    out[gid]   = v;
    outbf[gid] = f2bf(v);
    qbf[gid]   = f2bf(v + pv);
    pos[gid]   = pv;
}

// ---------------------------------------------------------------------------
// Weight transpose + bf16 convert:  W[K][N] fp32 -> Wt[N][K] bf16.
// ---------------------------------------------------------------------------
__global__ __launch_bounds__(256) void wconv_kernel(
    const float* __restrict__ Wv, const float* __restrict__ Woff,
    const float* __restrict__ Wa, const float* __restrict__ Wo,
    const float* __restrict__ W1, const float* __restrict__ W2,
    unsigned short* __restrict__ Wv_t, unsigned short* __restrict__ Woffa_t,
    unsigned short* __restrict__ Wo_t, unsigned short* __restrict__ W1_t,
    unsigned short* __restrict__ W2_t)
{
    __shared__ float tile[32][33];
    int bid = blockIdx.x;
    int layer = bid / 736, r = bid % 736;
    const float* src; unsigned short* dst;
    int N, tk, tn, dstRowOff = 0, dstLd;
    if (r < 64)       { src = Wv  + layer*65536;  dst = Wv_t   + layer*65536;  N = 256;  int t2 = r;       tk = t2 >> 3; tn = t2 & 7;  dstLd = 256;  }
    else if (r < 128) { src = Woff+ layer*65536;  dst = Woffa_t+ layer*98304;  N = 256;  int t2 = r - 64;  tk = t2 >> 3; tn = t2 & 7;  dstLd = 256;  }
    else if (r < 160) { src = Wa  + layer*32768;  dst = Woffa_t+ layer*98304;  N = 128;  int t2 = r - 128; tk = t2 >> 2; tn = t2 & 3;  dstLd = 256;  dstRowOff = 256; }
    else if (r < 224) { src = Wo  + layer*65536;  dst = Wo_t   + layer*65536;  N = 256;  int t2 = r - 160; tk = t2 >> 3; tn = t2 & 7;  dstLd = 256;  }
    else if (r < 480) { src = W1  + layer*262144; dst = W1_t   + layer*262144; N = 1024; int t2 = r - 224; tk = t2 >> 5; tn = t2 & 31; dstLd = 256;  }
    else              { src = W2  + layer*262144; dst = W2_t   + layer*262144; N = 256;  int t2 = r - 480; tk = t2 >> 3; tn = t2 & 7;  dstLd = 1024; }
    int k0 = tk * 32, n0 = tn * 32;
    int tx = threadIdx.x & 31, ty = threadIdx.x >> 5;
    #pragma unroll
    for (int i = 0; i < 4; ++i)
        tile[ty + i*8][tx] = src[(size_t)(k0 + ty + i*8) * N + n0 + tx];
    __syncthreads();
    #pragma unroll
    for (int i = 0; i < 4; ++i)
        dst[(size_t)(dstRowOff + n0 + ty + i*8) * dstLd + k0 + tx] =
            f2bf(tile[tx][ty + i*8]);
}

// ---------------------------------------------------------------------------
// Generic bf16 MFMA GEMM, BM=64 BN=64 BK=32, 256 thr / 4 waves (wave: 32x32).
// Double-buffered LDS with prefetch; [kchunk][row] layout (conflict-free).
// ---------------------------------------------------------------------------
template<bool RELU, bool OUTBF>
__global__ __launch_bounds__(256) void gemm2(
    const unsigned short* __restrict__ A, const unsigned short* __restrict__ Bt,
    const float* __restrict__ bias, const float* __restrict__ bias2, int split,
    void* __restrict__ Cout, int M, int N, int K)
{
    __shared__ __align__(16) char smem[16384];  // [buf: A 4KB | B 4KB] x2
    const int tid  = threadIdx.x;
    const int lane = tid & 63, wave = tid >> 6;
    const int wm = wave >> 1, wn = wave & 1;
    const int row0 = blockIdx.y * 64, col0 = blockIdx.x * 64;
    const int l15 = lane & 15, l4 = lane >> 4;

    // staging source pointers (u = tid: kb = u>>6, idx = u&63)
    const int kb = tid >> 6, ix = tid & 63;
    const unsigned short* aSrc = A  + (size_t)(row0 + ix) * K + kb * 8;
    const unsigned short* bSrc = Bt + (size_t)(col0 + ix) * K + kb * 8;
    char* aDst = smem + wave * 1024;           // + buf*8192
    char* bDst = smem + 4096 + wave * 1024;    // + buf*8192

    // fragment read offsets
    const int aOff0 = ((l4 * 64 + wm * 32 + l15) << 4);        // + mf*256, +buf*8192
    const int bOff0 = 4096 + ((l4 * 64 + wn * 32 + l15) << 4); // + nf*256, +buf*8192

    f32x4 acc[2][2] = {};

    GLDS(aSrc, aDst);
    GLDS(bSrc, bDst);
    __syncthreads();

    const int nk = K >> 5;
    for (int t = 0; t < nk; ++t) {
        const int bo = (t & 1) * 8192;
        if (t + 1 < nk) {
            const int nbo = ((t + 1) & 1) * 8192;
            GLDS(aSrc + ((t + 1) << 5), aDst + nbo);
            GLDS(bSrc + ((t + 1) << 5), bDst + nbo);
        }
        bf16x8 av[2], bv[2];
        av[0] = *(const bf16x8*)(smem + bo + aOff0);
        av[1] = *(const bf16x8*)(smem + bo + aOff0 + 256);
        bv[0] = *(const bf16x8*)(smem + bo + bOff0);
        bv[1] = *(const bf16x8*)(smem + bo + bOff0 + 256);
        #pragma unroll
        for (int mf = 0; mf < 2; ++mf)
            #pragma unroll
            for (int nf = 0; nf < 2; ++nf)
                acc[mf][nf] = __builtin_amdgcn_mfma_f32_16x16x32_bf16(
                    av[mf], bv[nf], acc[mf][nf], 0, 0, 0);
        __syncthreads();
    }

    #pragma unroll
    for (int nf = 0; nf < 2; ++nf) {
        int col = col0 + wn * 32 + nf * 16 + l15;
        float bb = (col < split) ? bias[col] : bias2[col - split];
        #pragma unroll
        for (int mf = 0; mf < 2; ++mf) {
            #pragma unroll
            for (int i = 0; i < 4; ++i) {
                int row = row0 + wm * 32 + mf * 16 + l4 * 4 + i;
                if (row < M) {
                    float v = acc[mf][nf][i] + bb;
                    if (RELU) v = fmaxf(v, 0.f);
                    if (OUTBF)
                        ((unsigned short*)Cout)[(size_t)row * N + col] = f2bf(v);
                    else
                        ((float*)Cout)[(size_t)row * N + col] = v;
                }
            }
        }
    }
}

// ---------------------------------------------------------------------------
// Fused GEMM (N=256) + residual add + LayerNorm epilogue.
// BM=32, BN=256, 512 thr / 8 waves (wave wn: 32 rows x 32 cols).
// Writes out fp32, outbf; if WITH_POS also qbf = bf16(LN + pos).
// ---------------------------------------------------------------------------
template<bool WITH_POS>
__global__ __launch_bounds__(512) void gemm_ln(
    const unsigned short* __restrict__ A, const unsigned short* __restrict__ Bt,
    const float* __restrict__ bias, const float* __restrict__ g,
    const float* __restrict__ be, const float* __restrict__ pos,
    float* __restrict__ out, unsigned short* __restrict__ outbf,
    unsigned short* __restrict__ qbf, int K)
{
    // [A: buf0 2KB | buf1 2KB][B: buf0 16KB | buf1 16KB][stats 2KB]
    __shared__ __align__(16) char smem[38912];
    float* st = (float*)(smem + 36864);
    const int tid  = threadIdx.x;
    const int lane = tid & 63, wave = tid >> 6;   // wave == wn (0..7)
    const int l15 = lane & 15, l4 = lane >> 4;
    const int row0 = blockIdx.x * 32;

    const unsigned short* aSrc = nullptr;
    char* aDst = nullptr;
    if (tid < 128) {
        int kb = tid >> 5, rr = tid & 31;
        aSrc = A + (size_t)(row0 + rr) * K + kb * 8;
        aDst = smem + wave * 1024;                  // + buf*2048
    }
    const unsigned short* bSrc0;
    const unsigned short* bSrc1;
    {
        int u0 = tid,        kb0 = u0 >> 8, c0 = u0 & 255;
        int u1 = 512 + tid,  kb1 = u1 >> 8, c1 = u1 & 255;
        bSrc0 = Bt + (size_t)c0 * K + kb0 * 8;
        bSrc1 = Bt + (size_t)c1 * K + kb1 * 8;
    }
    char* bDst0 = smem + 4096 + (wave * 64) * 16;          // + buf*16384
    char* bDst1 = smem + 4096 + (512 + wave * 64) * 16;    // + buf*16384

    const int aOff0 = ((l4 * 32 + l15) << 4);                         // + mf*256
    const int bOff0 = 4096 + ((l4 * 256 + wave * 32 + l15) << 4);     // + nf*256

    f32x4 acc[2][2] = {};

    if (aSrc) GLDS(aSrc, aDst);
    GLDS(bSrc0, bDst0);
    GLDS(bSrc1, bDst1);
    __syncthreads();

    const int nk = K >> 5;
    for (int t = 0; t < nk; ++t) {
        const int abo = (t & 1) * 2048, bbo = (t & 1) * 16384;
        if (t + 1 < nk) {
            const int nabo = ((t + 1) & 1) * 2048, nbbo = ((t + 1) & 1) * 16384;
            if (aSrc) GLDS(aSrc + ((t + 1) << 5), aDst + nabo);
            GLDS(bSrc0 + ((t + 1) << 5), bDst0 + nbbo);
            GLDS(bSrc1 + ((t + 1) << 5), bDst1 + nbbo);
        }
        bf16x8 av[2], bv[2];
        av[0] = *(const bf16x8*)(smem + abo + aOff0);
        av[1] = *(const bf16x8*)(smem + abo + aOff0 + 256);
        bv[0] = *(const bf16x8*)(smem + bbo + bOff0);
        bv[1] = *(const bf16x8*)(smem + bbo + bOff0 + 256);
        #pragma unroll
        for (int mf = 0; mf < 2; ++mf)
            #pragma unroll
            for (int nf = 0; nf < 2; ++nf)
                acc[mf][nf] = __builtin_amdgcn_mfma_f32_16x16x32_bf16(
                    av[mf], bv[nf], acc[mf][nf], 0, 0, 0);
        __syncthreads();
    }

    // epilogue: v = acc + bias + resid; per-row LN over 256 cols
    #pragma unroll
    for (int mf = 0; mf < 2; ++mf)
        #pragma unroll
        for (int i = 0; i < 4; ++i) {
            int row = row0 + mf * 16 + l4 * 4 + i;
            bool ok = row < MROWS;
            #pragma unroll
            for (int nf = 0; nf < 2; ++nf) {
                int col = wave * 32 + nf * 16 + l15;
                float r = ok ? out[(size_t)row * 256 + col] : 0.f;
                acc[mf][nf][i] += bias[col] + r;
            }
        }

    // per-(mf,i) row partial sums over this wave's 32 cols, reduce 16 lanes
    #pragma unroll
    for (int mf = 0; mf < 2; ++mf)
        #pragma unroll
        for (int i = 0; i < 4; ++i) {
            float s  = acc[mf][0][i] + acc[mf][1][i];
            float ss = acc[mf][0][i] * acc[mf][0][i]
                     + acc[mf][1][i] * acc[mf][1][i];
            #pragma unroll
            for (int m = 1; m < 16; m <<= 1) {
                s  += __shfl_xor(s, m);
                ss += __shfl_xor(ss, m);
            }
            if (l15 == 0) {
                int r = mf * 16 + l4 * 4 + i;
                st[wave * 32 + r]       = s;
                st[256 + wave * 32 + r] = ss;
            }
        }
    __syncthreads();

    #pragma unroll
    for (int mf = 0; mf < 2; ++mf)
        #pragma unroll
        for (int i = 0; i < 4; ++i) {
            int r = mf * 16 + l4 * 4 + i;
            float s = 0.f, ss = 0.f;
            #pragma unroll
            for (int w = 0; w < 8; ++w) {
                s  += st[w * 32 + r];
                ss += st[256 + w * 32 + r];
            }
            float mean = s * (1.f / 256.f);
            float var  = ss * (1.f / 256.f) - mean * mean;
            float rstd = rsqrtf(var + 1e-5f);
            int row = row0 + r;
            if (row >= MROWS) continue;
            #pragma unroll
            for (int nf = 0; nf < 2; ++nf) {
                int col = wave * 32 + nf * 16 + l15;
                float o = (acc[mf][nf][i] - mean) * rstd * g[col] + be[col];
                size_t idx = (size_t)row * 256 + col;
                out[idx]   = o;
                outbf[idx] = f2bf(o);
                if (WITH_POS) qbf[idx] = f2bf(o + pos[idx]);
            }
        }
}

// ---------------------------------------------------------------------------
// MSDA sampling (value in bf16). One thread per (b,t,head,quarter-of-HD).
// ---------------------------------------------------------------------------
__global__ __launch_bounds__(256) void msda_kernel(
    const unsigned short* __restrict__ value,  // (b*t, 256) bf16
    const float* __restrict__ offattn,         // (b*t, 384)
    unsigned short* __restrict__ outb)         // (b*t, 256) bf16
{
    int gid = blockIdx.x * 256 + threadIdx.x;
    if (gid >= MROWS * NHEAD * 8) return;
    int part = gid & 7;
    int h    = (gid >> 3) & 7;
    int bt   = gid >> 6;
    int b    = (bt >= LEN) ? 1 : 0;
    int t    = bt - b * LEN;

    const float* lg = offattn + (size_t)bt * 384 + 256 + h * 16;
    float w[16];
    float mx = -1e30f;
    #pragma unroll
    for (int j = 0; j < 16; ++j) { w[j] = lg[j]; mx = fmaxf(mx, w[j]); }
    float s = 0.f;
    #pragma unroll
    for (int j = 0; j < 16; ++j) { w[j] = __expf(w[j] - mx); s += w[j]; }
    float inv = 1.f / s;

    int li, Wr;
    if (t < 2304)      { li = t;        Wr = 48; }
    else if (t < 2880) { li = t - 2304; Wr = 24; }
    else if (t < 3024) { li = t - 2880; Wr = 12; }
    else               { li = t - 3024; Wr = 6;  }
    float refx = ((li % Wr) + 0.5f) / (float)Wr;
    float refy = ((li / Wr) + 0.5f) / (float)Wr;

    const float* offp = offattn + (size_t)bt * 384 + h * 32;
    const unsigned short* valbase =
        value + (size_t)b * LEN * D_MODEL + h * HDIM + part * 4;

    const int starts[4] = {0, 2304, 2880, 3024};
    const int Ws[4]     = {48, 24, 12, 6};

    float4 acc = make_float4(0.f, 0.f, 0.f, 0.f);

    #pragma unroll
    for (int lv = 0; lv < NLVL; ++lv) {
        int Wl = Ws[lv];
        int stt = starts[lv];
        float fW = (float)Wl;
        #pragma unroll
        for (int p = 0; p < NPTS; ++p) {
            float ox = offp[(lv * NPTS + p) * 2 + 0];
            float oy = offp[(lv * NPTS + p) * 2 + 1];
            float x = (refx + ox / fW) * fW - 0.5f;
            float y = (refy + oy / fW) * fW - 0.5f;
            float x0f = floorf(x), y0f = floorf(y);
            float lx = x - x0f, ly = y - y0f;
            int x0 = (int)x0f, y0 = (int)y0f;
            float aw = w[lv * NPTS + p] * inv;
            float tw[4] = {(1.f - lx) * (1.f - ly), lx * (1.f - ly),
                           (1.f - lx) * ly,         lx * ly};
            const int dxs[4] = {0, 1, 0, 1};
            const int dys[4] = {0, 0, 1, 1};
            #pragma unroll
            for (int tap = 0; tap < 4; ++tap) {
                int xi = x0 + dxs[tap], yi = y0 + dys[tap];
                bool valid = (xi >= 0) & (xi < Wl) & (yi >= 0) & (yi < Wl);
                int xc = xi < 0 ? 0 : (xi > Wl - 1 ? Wl - 1 : xi);
                int yc = yi < 0 ? 0 : (yi > Wl - 1 ? Wl - 1 : yi);
                int tt = stt + yc * Wl + xc;
                ushort4 vv = *(const ushort4*)(valbase + (size_t)tt * D_MODEL);
                float wt = valid ? aw * tw[tap] : 0.f;
                acc.x += wt * bf2f(vv.x); acc.y += wt * bf2f(vv.y);
                acc.z += wt * bf2f(vv.z); acc.w += wt * bf2f(vv.w);
            }
        }
    }
    ushort4 o = make_ushort4(f2bf(acc.x), f2bf(acc.y), f2bf(acc.z), f2bf(acc.w));
    *(ushort4*)(outb + (size_t)bt * D_MODEL + h * HDIM + part * 4) = o;
}

// ---------------------------------------------------------------------------
__global__ void tail_kernel(float* __restrict__ tail)
{
    if (threadIdx.x == 0 && blockIdx.x == 0) {
        const float vals[12] = {48.f, 48.f, 24.f, 24.f, 12.f, 12.f, 6.f, 6.f,
                                0.f, 2304.f, 2880.f, 3024.f};
        #pragma unroll
        for (int i = 0; i < 12; ++i) tail[i] = vals[i];
    }
}

// ---------------------------------------------------------------------------
extern "C" void kernel_launch(void* const* d_in, const int* in_sizes, int n_in,
                              void* d_out, int out_size, void* d_ws, size_t ws_size,
                              hipStream_t stream)
{
    const float* SRC[4]; const float* POS[4];
    bool interleaved = (in_sizes[1] == in_sizes[0]);
    if (interleaved) {
        SRC[0] = (const float*)d_in[0]; POS[0] = (const float*)d_in[1];
        SRC[1] = (const float*)d_in[2]; POS[1] = (const float*)d_in[3];
        SRC[2] = (const float*)d_in[4]; POS[2] = (const float*)d_in[5];
        SRC[3] = (const float*)d_in[6]; POS[3] = (const float*)d_in[7];
    } else {
        for (int i = 0; i < 4; ++i) {
            SRC[i] = (const float*)d_in[i];
            POS[i] = (const float*)d_in[4 + i];
        }
    }
    const float* lemb  = (const float*)d_in[8];
    const float* Wv    = (const float*)d_in[9];
    const float* bv    = (const float*)d_in[10];
    const float* Woff  = (const float*)d_in[11];
    const float* boff  = (const float*)d_in[12];
    const float* Wa    = (const float*)d_in[13];
    const float* ba    = (const float*)d_in[14];
    const float* Wo    = (const float*)d_in[15];
    const float* bo    = (const float*)d_in[16];
    const float* g1    = (const float*)d_in[17];
    const float* beta1 = (const float*)d_in[18];
    const float* W1    = (const float*)d_in[19];
    const float* bf1   = (const float*)d_in[20];
    const float* W2    = (const float*)d_in[21];
    const float* bf2   = (const float*)d_in[22];
    const float* g2    = (const float*)d_in[23];
    const float* beta2 = (const float*)d_in[24];

    float* out = (float*)d_out;                   // (b*t, 256) residual, fp32

    // ---- workspace layout ----
    char* ws = (char*)d_ws;
    float* pos     = (float*)ws;                   ws += (size_t)MPAD * 256 * 4;
    float* offattn = (float*)ws;                   ws += (size_t)MPAD * 384 * 4;
    unsigned short* qbf    = (unsigned short*)ws;  ws += (size_t)MPAD * 256 * 2;
    unsigned short* outbf  = (unsigned short*)ws;  ws += (size_t)MPAD * 256 * 2;
    unsigned short* msdabf = (unsigned short*)ws;  ws += (size_t)MPAD * 256 * 2;
    unsigned short* valbf  = (unsigned short*)ws;  ws += (size_t)MPAD * 256 * 2;
    unsigned short* hbuf   = (unsigned short*)ws;  ws += (size_t)MPAD * 1024 * 2;
    unsigned short* Wv_t    = (unsigned short*)ws; ws += (size_t)6 * 65536 * 2;
    unsigned short* Woffa_t = (unsigned short*)ws; ws += (size_t)6 * 98304 * 2;
    unsigned short* Wo_t    = (unsigned short*)ws; ws += (size_t)6 * 65536 * 2;
    unsigned short* W1_t    = (unsigned short*)ws; ws += (size_t)6 * 262144 * 2;
    unsigned short* W2_t    = (unsigned short*)ws; ws += (size_t)6 * 262144 * 2;

    wconv_kernel<<<6 * 736, 256, 0, stream>>>(Wv, Woff, Wa, Wo, W1, W2,
                                              Wv_t, Woffa_t, Wo_t, W1_t, W2_t);

    const int nElem = MROWS * D_MODEL;
    flatten_kernel<<<(nElem + 255) / 256, 256, 0, stream>>>(
        SRC[0], SRC[1], SRC[2], SRC[3], POS[0], POS[1], POS[2], POS[3],
        lemb, out, outbf, qbf, pos);

    const dim3 g256(4, MPAD / 64);     // (4, 96)
    const dim3 g384(6, MPAD / 64);     // (6, 96)
    const dim3 g1024(16, MPAD / 64);   // (16, 96)
    const int gLN = MPAD / 32;         // 192

    for (int l = 0; l < NLAYERS; ++l) {
        const unsigned short* Wv_l    = Wv_t    + (size_t)l * 65536;
        const unsigned short* Woffa_l = Woffa_t + (size_t)l * 98304;
        const unsigned short* Wo_l    = Wo_t    + (size_t)l * 65536;
        const unsigned short* W1_l    = W1_t    + (size_t)l * 262144;
        const unsigned short* W2_l    = W2_t    + (size_t)l * 262144;

        // value = out @ Wv + bv  (bf16 out)
        gemm2<false, true><<<g256, 256, 0, stream>>>(
            outbf, Wv_l, bv + l * 256, bv + l * 256, 256, valbf, MROWS, 256, 256);

        // [off | attn] = q @ [Woff | Wa] + [boff | ba]
        gemm2<false, false><<<g384, 256, 0, stream>>>(
            qbf, Woffa_l, boff + l * 256, ba + l * 128, 256, offattn, MROWS, 384, 256);

        // deformable sampling -> bf16
        msda_kernel<<<(MROWS * NHEAD * 8 + 255) / 256, 256, 0, stream>>>(
            valbf, offattn, msdabf);

        // out = LN(out + msda @ Wo + bo); also outbf
        gemm_ln<false><<<gLN, 512, 0, stream>>>(
            msdabf, Wo_l, bo + l * 256, g1 + l * 256, beta1 + l * 256, pos,
            out, outbf, qbf, 256);

        // h = relu(out @ W1 + bf1) -> bf16
        gemm2<true, true><<<g1024, 256, 0, stream>>>(
            outbf, W1_l, bf1 + l * DFF, bf1 + l * DFF, 1024, hbuf, MROWS, 1024, 256);

        // out = LN(out + h @ W2 + bf2); also outbf, qbf = bf16(out + pos)
        gemm_ln<true><<<gLN, 512, 0, stream>>>(
            hbuf, W2_l, bf2 + l * 256, g2 + l * 256, beta2 + l * 256, pos,
            out, outbf, qbf, 1024);
    }

    tail_kernel<<<1, 64, 0, stream>>>(out + (size_t)MROWS * D_MODEL);
}

// Round 4
// 731.817 us; speedup vs baseline: 1.0534x; 1.0534x over previous
//
#include <hip/hip_runtime.h>
#include <math.h>

#define D_MODEL 256
#define NHEAD 8
#define HDIM 32
#define NLVL 4
#define NPTS 4
#define DFF 1024
#define NLAYERS 6
#define LEN 3060
#define BS 2
#define MROWS (BS * LEN)   // 6120
#define MPAD 6144          // padded rows for GEMM A operands

typedef __attribute__((ext_vector_type(8))) short bf16x8;
typedef __attribute__((ext_vector_type(4))) float f32x4;

__device__ __forceinline__ unsigned short f2bf(float f) {
    union { float f; unsigned u; } v; v.f = f;
    unsigned r = v.u + 0x7FFF + ((v.u >> 16) & 1);
    return (unsigned short)(r >> 16);
}
__device__ __forceinline__ float bf2f(unsigned short s) {
    union { unsigned u; float f; } v; v.u = ((unsigned)s) << 16;
    return v.f;
}

#define GLDS(gp, lp) __builtin_amdgcn_global_load_lds(                        \
    (const __attribute__((address_space(1))) void*)(gp),                      \
    (__attribute__((address_space(3))) void*)(lp), 16, 0, 0)

// ---------------------------------------------------------------------------
// Flatten: src levels -> out fp32 + outbf + qbf(out+pos) + pos fp32
// ---------------------------------------------------------------------------
__global__ __launch_bounds__(256) void flatten_kernel(
    const float* __restrict__ s0, const float* __restrict__ s1,
    const float* __restrict__ s2, const float* __restrict__ s3,
    const float* __restrict__ p0, const float* __restrict__ p1,
    const float* __restrict__ p2, const float* __restrict__ p3,
    const float* __restrict__ lemb,
    float* __restrict__ out, unsigned short* __restrict__ outbf,
    unsigned short* __restrict__ qbf, float* __restrict__ pos)
{
    int gid = blockIdx.x * 256 + threadIdx.x;
    if (gid >= MROWS * D_MODEL) return;
    int d  = gid & (D_MODEL - 1);
    int bt = gid >> 8;
    int b  = (bt >= LEN) ? 1 : 0;
    int t  = bt - b * LEN;

    int lv, li, hw;
    const float* sp; const float* pp;
    if (t < 2304)      { lv = 0; li = t;        hw = 2304; sp = s0; pp = p0; }
    else if (t < 2880) { lv = 1; li = t - 2304; hw = 576;  sp = s1; pp = p1; }
    else if (t < 3024) { lv = 2; li = t - 2880; hw = 144;  sp = s2; pp = p2; }
    else               { lv = 3; li = t - 3024; hw = 36;   sp = s3; pp = p3; }

    size_t si = (size_t)(b * D_MODEL + d) * hw + li;
    float v = sp[si];
    float pv = pp[si] + lemb[lv * D_MODEL + d];
    out[gid]   = v;
    outbf[gid] = f2bf(v);
    qbf[gid]   = f2bf(v + pv);
    pos[gid]   = pv;
}

// ---------------------------------------------------------------------------
// Weight transpose + bf16 convert:  W[K][N] fp32 -> Wt[N][K] bf16.
// ---------------------------------------------------------------------------
__global__ __launch_bounds__(256) void wconv_kernel(
    const float* __restrict__ Wv, const float* __restrict__ Woff,
    const float* __restrict__ Wa, const float* __restrict__ Wo,
    const float* __restrict__ W1, const float* __restrict__ W2,
    unsigned short* __restrict__ Wv_t, unsigned short* __restrict__ Woffa_t,
    unsigned short* __restrict__ Wo_t, unsigned short* __restrict__ W1_t,
    unsigned short* __restrict__ W2_t)
{
    __shared__ float tile[32][33];
    int bid = blockIdx.x;
    int layer = bid / 736, r = bid % 736;
    const float* src; unsigned short* dst;
    int N, tk, tn, dstRowOff = 0, dstLd;
    if (r < 64)       { src = Wv  + layer*65536;  dst = Wv_t   + layer*65536;  N = 256;  int t2 = r;       tk = t2 >> 3; tn = t2 & 7;  dstLd = 256;  }
    else if (r < 128) { src = Woff+ layer*65536;  dst = Woffa_t+ layer*98304;  N = 256;  int t2 = r - 64;  tk = t2 >> 3; tn = t2 & 7;  dstLd = 256;  }
    else if (r < 160) { src = Wa  + layer*32768;  dst = Woffa_t+ layer*98304;  N = 128;  int t2 = r - 128; tk = t2 >> 2; tn = t2 & 3;  dstLd = 256;  dstRowOff = 256; }
    else if (r < 224) { src = Wo  + layer*65536;  dst = Wo_t   + layer*65536;  N = 256;  int t2 = r - 160; tk = t2 >> 3; tn = t2 & 7;  dstLd = 256;  }
    else if (r < 480) { src = W1  + layer*262144; dst = W1_t   + layer*262144; N = 1024; int t2 = r - 224; tk = t2 >> 5; tn = t2 & 31; dstLd = 256;  }
    else              { src = W2  + layer*262144; dst = W2_t   + layer*262144; N = 256;  int t2 = r - 480; tk = t2 >> 3; tn = t2 & 7;  dstLd = 1024; }
    int k0 = tk * 32, n0 = tn * 32;
    int tx = threadIdx.x & 31, ty = threadIdx.x >> 5;
    #pragma unroll
    for (int i = 0; i < 4; ++i)
        tile[ty + i*8][tx] = src[(size_t)(k0 + ty + i*8) * N + n0 + tx];
    __syncthreads();
    #pragma unroll
    for (int i = 0; i < 4; ++i)
        dst[(size_t)(dstRowOff + n0 + ty + i*8) * dstLd + k0 + tx] =
            f2bf(tile[tx][ty + i*8]);
}

// ---------------------------------------------------------------------------
// GEMM core: BM=128, BN=64, BK=64; 256 thr / 4 waves (2x2); wave tile 64x32
// = 4x2 fragments -> 16 MFMA per 12 ds_read_b128 per stage.
// LDS fragment-major: A chunk (q=k/8, r=row) at (q*128+r)*16; B at
// 16384+(q*64+n)*16. Double-buffered (+24576). All reads contiguous b128.
// ---------------------------------------------------------------------------
__device__ __forceinline__ void gemm_core(
    const unsigned short* __restrict__ A, const unsigned short* __restrict__ Bt,
    int row0, int col0, int K, char* smem, f32x4 (&acc)[4][2])
{
    const int tid  = threadIdx.x;
    const int lane = tid & 63, wave = tid >> 6;
    const int wm = wave >> 1, wn = wave & 1;
    const int l15 = lane & 15, l4 = lane >> 4;

    const unsigned short* aS[4]; const unsigned short* bS[2];
    int aD[4], bD[2];
    #pragma unroll
    for (int i = 0; i < 4; ++i) {
        int c = i*256 + tid, q = c >> 7, r = c & 127;
        aS[i] = A + (size_t)(row0 + r) * K + q*8;
        aD[i] = c * 16;
    }
    #pragma unroll
    for (int i = 0; i < 2; ++i) {
        int c = i*256 + tid, q = c >> 6, n = c & 63;
        bS[i] = Bt + (size_t)(col0 + n) * K + q*8;
        bD[i] = 16384 + c * 16;
    }

    int aOff[4][2], bOff[2][2];
    #pragma unroll
    for (int mf = 0; mf < 4; ++mf)
        #pragma unroll
        for (int s = 0; s < 2; ++s)
            aOff[mf][s] = ((s*4 + l4)*128 + wm*64 + mf*16 + l15) * 16;
    #pragma unroll
    for (int nf = 0; nf < 2; ++nf)
        #pragma unroll
        for (int s = 0; s < 2; ++s)
            bOff[nf][s] = 16384 + ((s*4 + l4)*64 + wn*32 + nf*16 + l15) * 16;

    #pragma unroll
    for (int i = 0; i < 4; ++i) GLDS(aS[i], smem + aD[i]);
    #pragma unroll
    for (int i = 0; i < 2; ++i) GLDS(bS[i], smem + bD[i]);
    __syncthreads();

    const int nt = K >> 6;
    for (int t = 0; t < nt; ++t) {
        const int bo = (t & 1) * 24576;
        if (t + 1 < nt) {
            const int nbo = ((t + 1) & 1) * 24576;
            const int k0 = (t + 1) << 6;
            #pragma unroll
            for (int i = 0; i < 4; ++i) GLDS(aS[i] + k0, smem + nbo + aD[i]);
            #pragma unroll
            for (int i = 0; i < 2; ++i) GLDS(bS[i] + k0, smem + nbo + bD[i]);
        }
        #pragma unroll
        for (int s = 0; s < 2; ++s) {
            bf16x8 bfr[2];
            #pragma unroll
            for (int nf = 0; nf < 2; ++nf)
                bfr[nf] = *(const bf16x8*)(smem + bo + bOff[nf][s]);
            #pragma unroll
            for (int mf = 0; mf < 4; ++mf) {
                bf16x8 afr = *(const bf16x8*)(smem + bo + aOff[mf][s]);
                #pragma unroll
                for (int nf = 0; nf < 2; ++nf)
                    acc[mf][nf] = __builtin_amdgcn_mfma_f32_16x16x32_bf16(
                        afr, bfr[nf], acc[mf][nf], 0, 0, 0);
            }
        }
        __syncthreads();
    }
}

// ---------------------------------------------------------------------------
template<bool RELU, bool OUTBF>
__global__ __launch_bounds__(256) void gemm3(
    const unsigned short* __restrict__ A, const unsigned short* __restrict__ Bt,
    const float* __restrict__ bias, void* __restrict__ Cout, int N, int K)
{
    __shared__ __align__(16) char smem[49152];
    f32x4 acc[4][2] = {};
    const int row0 = blockIdx.y * 128, col0 = blockIdx.x * 64;
    gemm_core(A, Bt, row0, col0, K, smem, acc);

    const int lane = threadIdx.x & 63, wave = threadIdx.x >> 6;
    const int wm = wave >> 1, wn = wave & 1;
    const int l15 = lane & 15, l4 = lane >> 4;
    #pragma unroll
    for (int nf = 0; nf < 2; ++nf) {
        int col = col0 + wn*32 + nf*16 + l15;
        float bb = bias[col];
        #pragma unroll
        for (int mf = 0; mf < 4; ++mf)
            #pragma unroll
            for (int i = 0; i < 4; ++i) {
                int row = row0 + wm*64 + mf*16 + l4*4 + i;
                if (row < MROWS) {
                    float v = acc[mf][nf][i] + bb;
                    if (RELU) v = fmaxf(v, 0.f);
                    if (OUTBF)
                        ((unsigned short*)Cout)[(size_t)row * N + col] = f2bf(v);
                    else
                        ((float*)Cout)[(size_t)row * N + col] = v;
                }
            }
    }
}

// ---------------------------------------------------------------------------
// Batched value + [off|attn] GEMM. blockIdx.x 0..3: value = outbf @ Wv -> bf16
// valbf (N=256). blockIdx.x 4..9: offattn = qbf @ [Woff|Wa] -> fp32 (N=384).
// ---------------------------------------------------------------------------
__global__ __launch_bounds__(256) void gemm_va(
    const unsigned short* __restrict__ outbf, const unsigned short* __restrict__ qbf,
    const unsigned short* __restrict__ Wv_l, const unsigned short* __restrict__ Woffa_l,
    const float* __restrict__ bv, const float* __restrict__ boff,
    const float* __restrict__ ba,
    unsigned short* __restrict__ valbf, float* __restrict__ offattn)
{
    __shared__ __align__(16) char smem[49152];
    const int bx = blockIdx.x;
    const bool isV = bx < 4;
    const unsigned short* A  = isV ? outbf : qbf;
    const unsigned short* Bt = isV ? Wv_l : Woffa_l;
    const int col0 = isV ? bx * 64 : (bx - 4) * 64;
    const int row0 = blockIdx.y * 128;

    f32x4 acc[4][2] = {};
    gemm_core(A, Bt, row0, col0, 256, smem, acc);

    const int lane = threadIdx.x & 63, wave = threadIdx.x >> 6;
    const int wm = wave >> 1, wn = wave & 1;
    const int l15 = lane & 15, l4 = lane >> 4;
    #pragma unroll
    for (int nf = 0; nf < 2; ++nf) {
        int col = col0 + wn*32 + nf*16 + l15;
        float bb = isV ? bv[col] : (col < 256 ? boff[col] : ba[col - 256]);
        #pragma unroll
        for (int mf = 0; mf < 4; ++mf)
            #pragma unroll
            for (int i = 0; i < 4; ++i) {
                int row = row0 + wm*64 + mf*16 + l4*4 + i;
                if (row < MROWS) {
                    float v = acc[mf][nf][i] + bb;
                    if (isV)
                        valbf[(size_t)row * 256 + col] = f2bf(v);
                    else
                        offattn[(size_t)row * 384 + col] = v;
                }
            }
    }
}

// ---------------------------------------------------------------------------
// MSDA sampling (value bf16). One thread per (b,t,head,quarter-of-HD).
// ---------------------------------------------------------------------------
__global__ __launch_bounds__(256) void msda_kernel(
    const unsigned short* __restrict__ value,  // (b*t, 256) bf16
    const float* __restrict__ offattn,         // (b*t, 384)
    unsigned short* __restrict__ outb)         // (b*t, 256) bf16
{
    int gid = blockIdx.x * 256 + threadIdx.x;
    if (gid >= MROWS * NHEAD * 8) return;
    int part = gid & 7;
    int h    = (gid >> 3) & 7;
    int bt   = gid >> 6;
    int b    = (bt >= LEN) ? 1 : 0;
    int t    = bt - b * LEN;

    const float* lg = offattn + (size_t)bt * 384 + 256 + h * 16;
    float w[16];
    float mx = -1e30f;
    #pragma unroll
    for (int j = 0; j < 16; ++j) { w[j] = lg[j]; mx = fmaxf(mx, w[j]); }
    float s = 0.f;
    #pragma unroll
    for (int j = 0; j < 16; ++j) { w[j] = __expf(w[j] - mx); s += w[j]; }
    float inv = 1.f / s;

    int li, Wr;
    if (t < 2304)      { li = t;        Wr = 48; }
    else if (t < 2880) { li = t - 2304; Wr = 24; }
    else if (t < 3024) { li = t - 2880; Wr = 12; }
    else               { li = t - 3024; Wr = 6;  }
    float refx = ((li % Wr) + 0.5f) / (float)Wr;
    float refy = ((li / Wr) + 0.5f) / (float)Wr;

    const float* offp = offattn + (size_t)bt * 384 + h * 32;
    const unsigned short* valbase =
        value + (size_t)b * LEN * D_MODEL + h * HDIM + part * 4;

    const int starts[4] = {0, 2304, 2880, 3024};
    const int Ws[4]     = {48, 24, 12, 6};

    float4 acc = make_float4(0.f, 0.f, 0.f, 0.f);

    #pragma unroll
    for (int lv = 0; lv < NLVL; ++lv) {
        int Wl = Ws[lv];
        int stt = starts[lv];
        float fW = (float)Wl;
        #pragma unroll
        for (int p = 0; p < NPTS; ++p) {
            float ox = offp[(lv * NPTS + p) * 2 + 0];
            float oy = offp[(lv * NPTS + p) * 2 + 1];
            float x = (refx + ox / fW) * fW - 0.5f;
            float y = (refy + oy / fW) * fW - 0.5f;
            float x0f = floorf(x), y0f = floorf(y);
            float lx = x - x0f, ly = y - y0f;
            int x0 = (int)x0f, y0 = (int)y0f;
            float aw = w[lv * NPTS + p] * inv;
            float tw[4] = {(1.f - lx) * (1.f - ly), lx * (1.f - ly),
                           (1.f - lx) * ly,         lx * ly};
            const int dxs[4] = {0, 1, 0, 1};
            const int dys[4] = {0, 0, 1, 1};
            #pragma unroll
            for (int tap = 0; tap < 4; ++tap) {
                int xi = x0 + dxs[tap], yi = y0 + dys[tap];
                bool valid = (xi >= 0) & (xi < Wl) & (yi >= 0) & (yi < Wl);
                int xc = xi < 0 ? 0 : (xi > Wl - 1 ? Wl - 1 : xi);
                int yc = yi < 0 ? 0 : (yi > Wl - 1 ? Wl - 1 : yi);
                int tt = stt + yc * Wl + xc;
                ushort4 vv = *(const ushort4*)(valbase + (size_t)tt * D_MODEL);
                float wt = valid ? aw * tw[tap] : 0.f;
                acc.x += wt * bf2f(vv.x); acc.y += wt * bf2f(vv.y);
                acc.z += wt * bf2f(vv.z); acc.w += wt * bf2f(vv.w);
            }
        }
    }
    ushort4 o = make_ushort4(f2bf(acc.x), f2bf(acc.y), f2bf(acc.z), f2bf(acc.w));
    *(ushort4*)(outb + (size_t)bt * D_MODEL + h * HDIM + part * 4) = o;
}

// ---------------------------------------------------------------------------
// Fused residual add + LayerNorm -> out fp32 (in place) + outbf;
// WITH_POS also qbf = bf16(LN + pos). One 64-lane wave per row.
// ---------------------------------------------------------------------------
template<bool WITH_POS>
__global__ __launch_bounds__(256) void add_ln_kernel(
    float* __restrict__ out, unsigned short* __restrict__ outbf,
    const float* __restrict__ add,
    const float* __restrict__ g, const float* __restrict__ be,
    const float* __restrict__ pos, unsigned short* __restrict__ qbf)
{
    int row  = blockIdx.x * 4 + (threadIdx.x >> 6);
    int lane = threadIdx.x & 63;
    if (row >= MROWS) return;

    float4 x = ((const float4*)(out + (size_t)row * D_MODEL))[lane];
    float4 y = ((const float4*)(add + (size_t)row * D_MODEL))[lane];
    x.x += y.x; x.y += y.y; x.z += y.z; x.w += y.w;

    float s  = x.x + x.y + x.z + x.w;
    float ss = x.x * x.x + x.y * x.y + x.z * x.z + x.w * x.w;
    #pragma unroll
    for (int m = 1; m < 64; m <<= 1) {
        s  += __shfl_xor(s, m);
        ss += __shfl_xor(ss, m);
    }
    float mean = s * (1.f / 256.f);
    float var  = ss * (1.f / 256.f) - mean * mean;
    float rstd = rsqrtf(var + 1e-5f);

    float4 gv = ((const float4*)g)[lane];
    float4 bv = ((const float4*)be)[lane];
    float4 o;
    o.x = (x.x - mean) * rstd * gv.x + bv.x;
    o.y = (x.y - mean) * rstd * gv.y + bv.y;
    o.z = (x.z - mean) * rstd * gv.z + bv.z;
    o.w = (x.w - mean) * rstd * gv.w + bv.w;
    ((float4*)(out + (size_t)row * D_MODEL))[lane] = o;
    ((ushort4*)(outbf + (size_t)row * D_MODEL))[lane] =
        make_ushort4(f2bf(o.x), f2bf(o.y), f2bf(o.z), f2bf(o.w));
    if (WITH_POS) {
        float4 pv = ((const float4*)(pos + (size_t)row * D_MODEL))[lane];
        ((ushort4*)(qbf + (size_t)row * D_MODEL))[lane] =
            make_ushort4(f2bf(o.x + pv.x), f2bf(o.y + pv.y),
                         f2bf(o.z + pv.z), f2bf(o.w + pv.w));
    }
}

// ---------------------------------------------------------------------------
__global__ void tail_kernel(float* __restrict__ tail)
{
    if (threadIdx.x == 0 && blockIdx.x == 0) {
        const float vals[12] = {48.f, 48.f, 24.f, 24.f, 12.f, 12.f, 6.f, 6.f,
                                0.f, 2304.f, 2880.f, 3024.f};
        #pragma unroll
        for (int i = 0; i < 12; ++i) tail[i] = vals[i];
    }
}

// ---------------------------------------------------------------------------
extern "C" void kernel_launch(void* const* d_in, const int* in_sizes, int n_in,
                              void* d_out, int out_size, void* d_ws, size_t ws_size,
                              hipStream_t stream)
{
    const float* SRC[4]; const float* POS[4];
    bool interleaved = (in_sizes[1] == in_sizes[0]);
    if (interleaved) {
        SRC[0] = (const float*)d_in[0]; POS[0] = (const float*)d_in[1];
        SRC[1] = (const float*)d_in[2]; POS[1] = (const float*)d_in[3];
        SRC[2] = (const float*)d_in[4]; POS[2] = (const float*)d_in[5];
        SRC[3] = (const float*)d_in[6]; POS[3] = (const float*)d_in[7];
    } else {
        for (int i = 0; i < 4; ++i) {
            SRC[i] = (const float*)d_in[i];
            POS[i] = (const float*)d_in[4 + i];
        }
    }
    const float* lemb  = (const float*)d_in[8];
    const float* Wv    = (const float*)d_in[9];
    const float* bv    = (const float*)d_in[10];
    const float* Woff  = (const float*)d_in[11];
    const float* boff  = (const float*)d_in[12];
    const float* Wa    = (const float*)d_in[13];
    const float* ba    = (const float*)d_in[14];
    const float* Wo    = (const float*)d_in[15];
    const float* bo    = (const float*)d_in[16];
    const float* g1    = (const float*)d_in[17];
    const float* beta1 = (const float*)d_in[18];
    const float* W1    = (const float*)d_in[19];
    const float* bf1   = (const float*)d_in[20];
    const float* W2    = (const float*)d_in[21];
    const float* bf2   = (const float*)d_in[22];
    const float* g2    = (const float*)d_in[23];
    const float* beta2 = (const float*)d_in[24];

    float* out = (float*)d_out;                   // (b*t, 256) residual, fp32

    // ---- workspace layout ----
    char* ws = (char*)d_ws;
    float* pos     = (float*)ws;                   ws += (size_t)MPAD * 256 * 4;
    float* offattn = (float*)ws;                   ws += (size_t)MPAD * 384 * 4;
    float* tmp     = (float*)ws;                   ws += (size_t)MPAD * 256 * 4;
    unsigned short* qbf    = (unsigned short*)ws;  ws += (size_t)MPAD * 256 * 2;
    unsigned short* outbf  = (unsigned short*)ws;  ws += (size_t)MPAD * 256 * 2;
    unsigned short* msdabf = (unsigned short*)ws;  ws += (size_t)MPAD * 256 * 2;
    unsigned short* valbf  = (unsigned short*)ws;  ws += (size_t)MPAD * 256 * 2;
    unsigned short* hbuf   = (unsigned short*)ws;  ws += (size_t)MPAD * 1024 * 2;
    unsigned short* Wv_t    = (unsigned short*)ws; ws += (size_t)6 * 65536 * 2;
    unsigned short* Woffa_t = (unsigned short*)ws; ws += (size_t)6 * 98304 * 2;
    unsigned short* Wo_t    = (unsigned short*)ws; ws += (size_t)6 * 65536 * 2;
    unsigned short* W1_t    = (unsigned short*)ws; ws += (size_t)6 * 262144 * 2;
    unsigned short* W2_t    = (unsigned short*)ws; ws += (size_t)6 * 262144 * 2;

    wconv_kernel<<<6 * 736, 256, 0, stream>>>(Wv, Woff, Wa, Wo, W1, W2,
                                              Wv_t, Woffa_t, Wo_t, W1_t, W2_t);

    const int nElem = MROWS * D_MODEL;
    flatten_kernel<<<(nElem + 255) / 256, 256, 0, stream>>>(
        SRC[0], SRC[1], SRC[2], SRC[3], POS[0], POS[1], POS[2], POS[3],
        lemb, out, outbf, qbf, pos);

    const dim3 gVA(10, MPAD / 128);     // (10, 48) = 480 blocks
    const dim3 g256(4, MPAD / 128);     // 192 blocks
    const dim3 g1024(16, MPAD / 128);   // 768 blocks
    const int gLN = MROWS / 4;          // 1530

    for (int l = 0; l < NLAYERS; ++l) {
        const unsigned short* Wv_l    = Wv_t    + (size_t)l * 65536;
        const unsigned short* Woffa_l = Woffa_t + (size_t)l * 98304;
        const unsigned short* Wo_l    = Wo_t    + (size_t)l * 65536;
        const unsigned short* W1_l    = W1_t    + (size_t)l * 262144;
        const unsigned short* W2_l    = W2_t    + (size_t)l * 262144;

        // value (bf16) + [off|attn] (fp32), one launch
        gemm_va<<<gVA, 256, 0, stream>>>(
            outbf, qbf, Wv_l, Woffa_l, bv + l * 256, boff + l * 256,
            ba + l * 128, valbf, offattn);

        // deformable sampling -> bf16
        msda_kernel<<<(MROWS * NHEAD * 8 + 255) / 256, 256, 0, stream>>>(
            valbf, offattn, msdabf);

        // out-proj: tmp = msda @ Wo + bo
        gemm3<false, false><<<g256, 256, 0, stream>>>(
            msdabf, Wo_l, bo + l * 256, tmp, 256, 256);

        // out = LN(out + tmp)
        add_ln_kernel<false><<<gLN, 256, 0, stream>>>(
            out, outbf, tmp, g1 + l * 256, beta1 + l * 256, pos, qbf);

        // h = relu(out @ W1 + bf1) -> bf16
        gemm3<true, true><<<g1024, 256, 0, stream>>>(
            outbf, W1_l, bf1 + l * DFF, hbuf, 1024, 256);

        // tmp = h @ W2 + bf2
        gemm3<false, false><<<g256, 256, 0, stream>>>(
            hbuf, W2_l, bf2 + l * 256, tmp, 256, 1024);

        // out = LN(out + tmp); qbf = bf16(out + pos)
        add_ln_kernel<true><<<gLN, 256, 0, stream>>>(
            out, outbf, tmp, g2 + l * 256, beta2 + l * 256, pos, qbf);
    }

    tail_kernel<<<1, 64, 0, stream>>>(out + (size_t)MROWS * D_MODEL);
}